// Round 2
// baseline (169.646 us; speedup 1.0000x reference)
//
#include <hip/hip_runtime.h>
#include <hip/hip_bf16.h>
#include <stdint.h>

typedef __attribute__((ext_vector_type(8))) short short8;
typedef __attribute__((ext_vector_type(4))) short short4v;
typedef __attribute__((ext_vector_type(4))) float float4v;

#define MFMA16(a,b,c) __builtin_amdgcn_mfma_f32_16x16x32_bf16((a),(b),(c),0,0,0)

__device__ __forceinline__ short bf16r(float f) {
  union { float f; uint32_t u; } v; v.f = f;
  uint32_t r = v.u + 0x7fffu + ((v.u >> 16) & 1u);
  return (short)(r >> 16);
}

// ---------------- Kernel 1: W transpose+convert -> WT bf16 [3][64][1024] ----
__global__ __launch_bounds__(256) void prep_wt(
    const float* __restrict__ Wk, const float* __restrict__ Wq,
    const float* __restrict__ Wv, short* __restrict__ WT) {
  int idx = blockIdx.x * 256 + threadIdx.x;   // 0 .. 3*64*1024-1
  int w = idx >> 16;
  int rem = idx & 65535;
  int h = rem >> 10;
  int k = rem & 1023;
  const float* W = (w == 0) ? Wk : (w == 1) ? Wq : Wv;
  WT[idx] = bf16r(W[k * 64 + h]);
}

// ---------------- Kernel 2: projection GEMM (bf16 MFMA) --------------------
// x[16384][1024] fp32 @ WT[192][1024] bf16 -> Kg/Qg [16384][64] bf16,
// Vt [4][64][4096] bf16 (transposed for attention B-fragments).
// 512 threads = 8 waves: rows (w&3)*16, n-half (w>>2)*96 (6 n-tiles each).
// x staged via reg double-buffer -> LDS bf16; WT B-frags read direct (L2).
__global__ __launch_bounds__(512) void proj_kernel(
    const float* __restrict__ x, const short* __restrict__ WT,
    short* __restrict__ Kg, short* __restrict__ Qg, short* __restrict__ Vt) {
  __shared__ __align__(16) short xs[64][72];   // +8 pad -> 2-way reads (free)
  const int tid = threadIdx.x;
  const int lane = tid & 63;
  const int w = tid >> 6;
  const int c = lane & 15;
  const int sl = lane >> 4;
  const int r0 = (w & 3) * 16;
  const int nh = w >> 2;                       // 0 or 1
  const int m0 = blockIdx.x * 64;

  float4v acc[6];
#pragma unroll
  for (int i = 0; i < 6; ++i) acc[i] = (float4v){0.f, 0.f, 0.f, 0.f};

  const int srow = tid >> 3;                   // 0..63
  const int scol = (tid & 7) * 8;              // 8 floats/thread
  const float* xrow = x + (size_t)(m0 + srow) * 1024 + scol;

  float4v xr0 = *(const float4v*)(xrow);
  float4v xr1 = *(const float4v*)(xrow + 4);

  for (int k0 = 0; k0 < 1024; k0 += 64) {
    // B-frags for this step: direct from global (L2-resident), issued early
    short8 bf[6][2];
#pragma unroll
    for (int nt = 0; nt < 6; ++nt) {
      const short* bp = WT + (size_t)(nh * 96 + nt * 16 + c) * 1024 + k0 + sl * 8;
      bf[nt][0] = *(const short8*)(bp);
      bf[nt][1] = *(const short8*)(bp + 32);
    }
    __syncthreads();                           // prev step's xs reads done
    {
      short8 hx;
      hx[0] = bf16r(xr0.x); hx[1] = bf16r(xr0.y);
      hx[2] = bf16r(xr0.z); hx[3] = bf16r(xr0.w);
      hx[4] = bf16r(xr1.x); hx[5] = bf16r(xr1.y);
      hx[6] = bf16r(xr1.z); hx[7] = bf16r(xr1.w);
      *(short8*)(&xs[srow][scol]) = hx;
    }
    __syncthreads();
    if (k0 + 64 < 1024) {                      // prefetch next x tile (regs)
      xr0 = *(const float4v*)(xrow + k0 + 64);
      xr1 = *(const float4v*)(xrow + k0 + 68);
    }
    short8 a0 = *(const short8*)(&xs[r0 + c][sl * 8]);
    short8 a1 = *(const short8*)(&xs[r0 + c][32 + sl * 8]);
#pragma unroll
    for (int nt = 0; nt < 6; ++nt) {
      acc[nt] = MFMA16(a0, bf[nt][0], acc[nt]);
      acc[nt] = MFMA16(a1, bf[nt][1], acc[nt]);
    }
  }

  const int b = m0 >> 12;
  const int s_base = m0 & 4095;
  const int q_local = r0 + sl * 4;
#pragma unroll
  for (int nt = 0; nt < 6; ++nt) {
    const int nb = nh * 96 + nt * 16;
    const int wsel = nb >> 6;                  // 0:K 1:Q 2:V
    const int h = (nb & 63) + c;
    if (wsel == 2) {                           // V transposed: 4 consecutive s
      short4v pv;
      pv.x = bf16r(acc[nt].x); pv.y = bf16r(acc[nt].y);
      pv.z = bf16r(acc[nt].z); pv.w = bf16r(acc[nt].w);
      *(short4v*)(Vt + (size_t)(b * 64 + h) * 4096 + s_base + q_local) = pv;
    } else {
      short* outp = (wsel == 0) ? Kg : Qg;
#pragma unroll
      for (int i = 0; i < 4; ++i)
        outp[(size_t)(m0 + q_local + i) * 64 + h] = bf16r(acc[nt][i]);
    }
  }
}

// ---------------- Kernel 3: flash attention, 1 wave per 16 q-rows -----------
// grid (256, 4), block 64. No barriers; K/V B-frags direct from global (L2).
__global__ __launch_bounds__(64) void attn_kernel(
    const short* __restrict__ Qg, const short* __restrict__ Kg,
    const short* __restrict__ Vt, float* __restrict__ out) {
  __shared__ __align__(16) short Ps[16][72];   // wave-private P relayout
  const int lane = threadIdx.x;
  const int c = lane & 15;
  const int sl = lane >> 4;
  const int g = blockIdx.x;                    // q-group 0..255
  const int b = blockIdx.y;
  const int qw = g * 16;
  const int T = (g >> 2) + 1;                  // # of 64-wide KV tiles

  const short* Kb = Kg + (size_t)b * 4096 * 64;
  const short* Vb = Vt + (size_t)b * 64 * 4096;

  short8 aq0, aq1;
  {
    const short* qp = Qg + (size_t)(b * 4096 + qw + c) * 64 + sl * 8;
    aq0 = *(const short8*)(qp);
    aq1 = *(const short8*)(qp + 32);
  }

  float4v o[4];
#pragma unroll
  for (int i = 0; i < 4; ++i) o[i] = (float4v){0.f, 0.f, 0.f, 0.f};
  float mrun[4] = {-1e30f, -1e30f, -1e30f, -1e30f};
  float lsum[4] = {0.f, 0.f, 0.f, 0.f};
  const float scale = 0.125f;

  // preload K tile 0 B-frags
  short8 kb[4][2];
#pragma unroll
  for (int nt = 0; nt < 4; ++nt) {
    const short* kp = Kb + (size_t)(nt * 16 + c) * 64 + sl * 8;
    kb[nt][0] = *(const short8*)(kp);
    kb[nt][1] = *(const short8*)(kp + 32);
  }

  for (int t = 0; t < T; ++t) {
    const int kv0 = t * 64;

    // V B-frags for this tile (consumed after softmax, ~400cy of cover)
    short8 vb[4][2];
#pragma unroll
    for (int ht = 0; ht < 4; ++ht) {
      const short* vp = Vb + (size_t)(ht * 16 + c) * 4096 + kv0 + sl * 8;
      vb[ht][0] = *(const short8*)(vp);
      vb[ht][1] = *(const short8*)(vp + 32);
    }

    // S = Q K^T
    float4v s[4];
#pragma unroll
    for (int nt = 0; nt < 4; ++nt) {
      float4v z = {0.f, 0.f, 0.f, 0.f};
      z = MFMA16(aq0, kb[nt][0], z);
      z = MFMA16(aq1, kb[nt][1], z);
      s[nt] = z;
    }

    // prefetch K tile t+1 (covered by softmax + PV + next-iter head)
    if (t + 1 < T) {
#pragma unroll
      for (int nt = 0; nt < 4; ++nt) {
        const short* kp = Kb + (size_t)(kv0 + 64 + nt * 16 + c) * 64 + sl * 8;
        kb[nt][0] = *(const short8*)(kp);
        kb[nt][1] = *(const short8*)(kp + 32);
      }
    }

    // scale + causal mask (last tile only)
    if (t == T - 1) {
#pragma unroll
      for (int nt = 0; nt < 4; ++nt) {
        const int kvg = kv0 + nt * 16 + c;
#pragma unroll
        for (int i = 0; i < 4; ++i) {
          const int qg = qw + sl * 4 + i;
          float v = s[nt][i] * scale;
          s[nt][i] = (kvg <= qg) ? v : -1e30f;
        }
      }
    } else {
#pragma unroll
      for (int nt = 0; nt < 4; ++nt)
#pragma unroll
        for (int i = 0; i < 4; ++i) s[nt][i] *= scale;
    }

    // online softmax: each q-row spans the 16 lanes of its sl-group
    float pm[4];
#pragma unroll
    for (int i = 0; i < 4; ++i)
      pm[i] = fmaxf(fmaxf(s[0][i], s[1][i]), fmaxf(s[2][i], s[3][i]));
#pragma unroll
    for (int off = 1; off <= 8; off <<= 1)
#pragma unroll
      for (int i = 0; i < 4; ++i) pm[i] = fmaxf(pm[i], __shfl_xor(pm[i], off));

    float alpha[4];
#pragma unroll
    for (int i = 0; i < 4; ++i) {
      const float mn = fmaxf(mrun[i], pm[i]);
      alpha[i] = __expf(mrun[i] - mn);
      mrun[i] = mn;
    }
#pragma unroll
    for (int nt = 0; nt < 4; ++nt)
#pragma unroll
      for (int i = 0; i < 4; ++i) s[nt][i] = __expf(s[nt][i] - mrun[i]);

    float rs[4];
#pragma unroll
    for (int i = 0; i < 4; ++i) rs[i] = (s[0][i] + s[1][i]) + (s[2][i] + s[3][i]);
#pragma unroll
    for (int off = 1; off <= 8; off <<= 1)
#pragma unroll
      for (int i = 0; i < 4; ++i) rs[i] += __shfl_xor(rs[i], off);
#pragma unroll
    for (int i = 0; i < 4; ++i) lsum[i] = lsum[i] * alpha[i] + rs[i];

#pragma unroll
    for (int ht = 0; ht < 4; ++ht)
#pragma unroll
      for (int i = 0; i < 4; ++i) o[ht][i] *= alpha[i];

    // P -> bf16 -> wave-private LDS (A-frag relayout); no barrier needed
#pragma unroll
    for (int nt = 0; nt < 4; ++nt)
#pragma unroll
      for (int i = 0; i < 4; ++i)
        Ps[sl * 4 + i][nt * 16 + c] = bf16r(s[nt][i]);

    short8 ap0 = *(const short8*)(&Ps[c][sl * 8]);
    short8 ap1 = *(const short8*)(&Ps[c][32 + sl * 8]);

    // O += P V
#pragma unroll
    for (int ht = 0; ht < 4; ++ht) {
      o[ht] = MFMA16(ap0, vb[ht][0], o[ht]);
      o[ht] = MFMA16(ap1, vb[ht][1], o[ht]);
    }
  }

  float inv[4];
#pragma unroll
  for (int i = 0; i < 4; ++i) inv[i] = 1.0f / lsum[i];
#pragma unroll
  for (int ht = 0; ht < 4; ++ht)
#pragma unroll
    for (int i = 0; i < 4; ++i) {
      const int q = qw + sl * 4 + i;
      out[(size_t)(b * 4096 + q) * 64 + ht * 16 + c] = o[ht][i] * inv[i];
    }
}

extern "C" void kernel_launch(void* const* d_in, const int* in_sizes, int n_in,
                              void* d_out, int out_size, void* d_ws, size_t ws_size,
                              hipStream_t stream) {
  const float* x  = (const float*)d_in[0];
  const float* Wk = (const float*)d_in[1];
  const float* Wq = (const float*)d_in[2];
  const float* Wv = (const float*)d_in[3];

  char* ws = (char*)d_ws;
  short* WT = (short*)ws;                                  // 393216 B
  short* Kg = (short*)(ws + 393216);                       // 2 MB
  short* Qg = (short*)(ws + 393216 + 2097152);             // 2 MB
  short* Vt = (short*)(ws + 393216 + 2 * 2097152);         // 2 MB

  prep_wt<<<dim3(768), dim3(256), 0, stream>>>(Wk, Wq, Wv, WT);
  proj_kernel<<<dim3(256), dim3(512), 0, stream>>>(x, WT, Kg, Qg, Vt);
  attn_kernel<<<dim3(256, 4), dim3(64), 0, stream>>>(Qg, Kg, Vt, (float*)d_out);
}

// Round 3
// 111.577 us; speedup vs baseline: 1.5204x; 1.5204x over previous
//
#include <hip/hip_runtime.h>
#include <hip/hip_bf16.h>
#include <stdint.h>

typedef __attribute__((ext_vector_type(8))) short short8;
typedef __attribute__((ext_vector_type(4))) short short4v;
typedef __attribute__((ext_vector_type(4))) float float4v;

#define MFMA16(a,b,c) __builtin_amdgcn_mfma_f32_16x16x32_bf16((a),(b),(c),0,0,0)

__device__ __forceinline__ short bf16r(float f) {
  union { float f; uint32_t u; } v; v.f = f;
  uint32_t r = v.u + 0x7fffu + ((v.u >> 16) & 1u);
  return (short)(r >> 16);
}

__device__ __forceinline__ void gld_lds16(void* lds, const void* g) {
  __builtin_amdgcn_global_load_lds(
      (const __attribute__((address_space(1))) uint32_t*)g,
      (__attribute__((address_space(3))) uint32_t*)lds, 16, 0, 0);
}

// ---------------- Kernel 1: W transpose+convert -> WT bf16 [3][64][1024] ----
__global__ __launch_bounds__(256) void prep_wt(
    const float* __restrict__ Wk, const float* __restrict__ Wq,
    const float* __restrict__ Wv, short* __restrict__ WT) {
  int idx = blockIdx.x * 256 + threadIdx.x;   // 0 .. 3*64*1024-1
  int w = idx >> 16;
  int rem = idx & 65535;
  int h = rem >> 10;
  int k = rem & 1023;
  const float* W = (w == 0) ? Wk : (w == 1) ? Wq : Wv;
  WT[idx] = bf16r(W[k * 64 + h]);
}

// ---------------- Kernel 2: projection GEMM (bf16 MFMA) --------------------
// x[16384][1024] fp32 @ WT[192][1024] bf16 -> Kg/Qg [16384][64] bf16,
// Vt [4][64][4096] bf16. 512 thr = 8 waves: m-group (w&3)*16, n-half w>>2.
// WT tile staged to LDS via global_load_lds (XOR-swizzled source columns).
__global__ __launch_bounds__(512) void proj_kernel(
    const float* __restrict__ x, const short* __restrict__ WT,
    short* __restrict__ Kg, short* __restrict__ Qg, short* __restrict__ Vt) {
  __shared__ __align__(16) short xs[64][72];      // +8 pad -> 2-way (free)
  __shared__ __align__(16) short wts[192 * 64];   // linear, swizzled content
  const int tid = threadIdx.x;
  const int lane = tid & 63;
  const int w = tid >> 6;
  const int c = lane & 15;
  const int sl = lane >> 4;
  const int r0 = (w & 3) * 16;
  const int nh = w >> 2;                          // 0 or 1
  const int m0 = blockIdx.x * 64;

  float4v acc[6];
#pragma unroll
  for (int i = 0; i < 6; ++i) acc[i] = (float4v){0.f, 0.f, 0.f, 0.f};

  const int srow = tid >> 3;                      // 0..63
  const int scol = (tid & 7) * 8;                 // 8 floats/thread
  const float* xrow = x + (size_t)(m0 + srow) * 1024 + scol;

  float4v xr0 = *(const float4v*)(xrow);
  float4v xr1 = *(const float4v*)(xrow + 4);

  for (int k0 = 0; k0 < 1024; k0 += 64) {
    __syncthreads();                              // prev step's reads done
#pragma unroll
    for (int rr = 0; rr < 3; ++rr) {              // stage WT 192x64 (async)
      const int chunk = rr * 512 + tid;
      const int n = chunk >> 3;
      const int cc = chunk & 7;
      gld_lds16(wts + chunk * 8,
                WT + (size_t)n * 1024 + k0 + ((cc ^ (n & 7)) * 8));
    }
    {                                             // stage x tile -> bf16
      short8 hx;
      hx[0] = bf16r(xr0.x); hx[1] = bf16r(xr0.y);
      hx[2] = bf16r(xr0.z); hx[3] = bf16r(xr0.w);
      hx[4] = bf16r(xr1.x); hx[5] = bf16r(xr1.y);
      hx[6] = bf16r(xr1.z); hx[7] = bf16r(xr1.w);
      *(short8*)(&xs[srow][scol]) = hx;
    }
    __syncthreads();                              // drains vmcnt (gld_lds)
    if (k0 + 64 < 1024) {                         // prefetch next x (regs)
      xr0 = *(const float4v*)(xrow + k0 + 64);
      xr1 = *(const float4v*)(xrow + k0 + 68);
    }
    short8 a0 = *(const short8*)(&xs[r0 + c][sl * 8]);
    short8 a1 = *(const short8*)(&xs[r0 + c][32 + sl * 8]);
#pragma unroll
    for (int nt = 0; nt < 6; ++nt) {
      const int row = nh * 96 + nt * 16 + c;
      short8 b0 = *(const short8*)(wts + row * 64 + ((sl ^ (row & 7)) * 8));
      short8 b1 = *(const short8*)(wts + row * 64 + (((sl + 4) ^ (row & 7)) * 8));
      acc[nt] = MFMA16(a0, b0, acc[nt]);
      acc[nt] = MFMA16(a1, b1, acc[nt]);
    }
  }

  const int b = m0 >> 12;
  const int s_base = m0 & 4095;
  const int q_local = r0 + sl * 4;
#pragma unroll
  for (int nt = 0; nt < 6; ++nt) {
    const int nb = nh * 96 + nt * 16;
    const int wsel = nb >> 6;                     // 0:K 1:Q 2:V
    const int h = (nb & 63) + c;
    if (wsel == 2) {
      short4v pv;
      pv.x = bf16r(acc[nt].x); pv.y = bf16r(acc[nt].y);
      pv.z = bf16r(acc[nt].z); pv.w = bf16r(acc[nt].w);
      *(short4v*)(Vt + (size_t)(b * 64 + h) * 4096 + s_base + q_local) = pv;
    } else {
      short* outp = (wsel == 0) ? Kg : Qg;
#pragma unroll
      for (int i = 0; i < 4; ++i)
        outp[(size_t)(m0 + q_local + i) * 64 + h] = bf16r(acc[nt][i]);
    }
  }
}

// ---------------- Kernel 3: flash attention, split-KV ----------------------
// grid (256, 4, maxch), block 64. Chunk ch covers KV tiles [ch*C, min(+C,T)).
// Writes unnormalized partial (o, m, l) to ws; combine_kernel reduces.
#define PART_STRIDE 1056   // floats: 16x64 o + 16 m + 16 l
__global__ __launch_bounds__(64) void attn_kernel(
    const short* __restrict__ Qg, const short* __restrict__ Kg,
    const short* __restrict__ Vt, float* __restrict__ out,
    float* __restrict__ part, int C, int maxch, int direct) {
  __shared__ __align__(16) short Ps[16][72];
  const int lane = threadIdx.x;
  const int c = lane & 15;
  const int sl = lane >> 4;
  const int g = blockIdx.x;
  const int b = blockIdx.y;
  const int ch = blockIdx.z;
  const int qw = g * 16;
  const int T = (g >> 2) + 1;                     // total 64-wide KV tiles
  const int c0 = ch * C;
  if (c0 >= T) return;
  const int c1 = (c0 + C < T) ? (c0 + C) : T;

  const short* Kb = Kg + (size_t)b * 4096 * 64;
  const short* Vb = Vt + (size_t)b * 64 * 4096;

  short8 aq0, aq1;
  {
    const short* qp = Qg + (size_t)(b * 4096 + qw + c) * 64 + sl * 8;
    aq0 = *(const short8*)(qp);
    aq1 = *(const short8*)(qp + 32);
  }

  float4v o[4];
#pragma unroll
  for (int i = 0; i < 4; ++i) o[i] = (float4v){0.f, 0.f, 0.f, 0.f};
  float mrun[4] = {-1e30f, -1e30f, -1e30f, -1e30f};
  float lsum[4] = {0.f, 0.f, 0.f, 0.f};
  const float scale = 0.125f;

  // preload K tile c0
  short8 kb[4][2];
#pragma unroll
  for (int nt = 0; nt < 4; ++nt) {
    const short* kp = Kb + (size_t)(c0 * 64 + nt * 16 + c) * 64 + sl * 8;
    kb[nt][0] = *(const short8*)(kp);
    kb[nt][1] = *(const short8*)(kp + 32);
  }

  for (int t = c0; t < c1; ++t) {
    const int kv0 = t * 64;

    short8 vb[4][2];
#pragma unroll
    for (int ht = 0; ht < 4; ++ht) {
      const short* vp = Vb + (size_t)(ht * 16 + c) * 4096 + kv0 + sl * 8;
      vb[ht][0] = *(const short8*)(vp);
      vb[ht][1] = *(const short8*)(vp + 32);
    }

    float4v s[4];
#pragma unroll
    for (int nt = 0; nt < 4; ++nt) {
      float4v z = {0.f, 0.f, 0.f, 0.f};
      z = MFMA16(aq0, kb[nt][0], z);
      z = MFMA16(aq1, kb[nt][1], z);
      s[nt] = z;
    }

    if (t + 1 < c1) {                             // prefetch next K tile
#pragma unroll
      for (int nt = 0; nt < 4; ++nt) {
        const short* kp = Kb + (size_t)(kv0 + 64 + nt * 16 + c) * 64 + sl * 8;
        kb[nt][0] = *(const short8*)(kp);
        kb[nt][1] = *(const short8*)(kp + 32);
      }
    }

    if (t == T - 1) {                             // diagonal tile: mask
#pragma unroll
      for (int nt = 0; nt < 4; ++nt) {
        const int kvg = kv0 + nt * 16 + c;
#pragma unroll
        for (int i = 0; i < 4; ++i) {
          const int qg = qw + sl * 4 + i;
          float v = s[nt][i] * scale;
          s[nt][i] = (kvg <= qg) ? v : -1e30f;
        }
      }
    } else {
#pragma unroll
      for (int nt = 0; nt < 4; ++nt)
#pragma unroll
        for (int i = 0; i < 4; ++i) s[nt][i] *= scale;
    }

    float pm[4];
#pragma unroll
    for (int i = 0; i < 4; ++i)
      pm[i] = fmaxf(fmaxf(s[0][i], s[1][i]), fmaxf(s[2][i], s[3][i]));
#pragma unroll
    for (int off = 1; off <= 8; off <<= 1)
#pragma unroll
      for (int i = 0; i < 4; ++i) pm[i] = fmaxf(pm[i], __shfl_xor(pm[i], off));

    float alpha[4];
#pragma unroll
    for (int i = 0; i < 4; ++i) {
      const float mn = fmaxf(mrun[i], pm[i]);
      alpha[i] = __expf(mrun[i] - mn);
      mrun[i] = mn;
    }
#pragma unroll
    for (int nt = 0; nt < 4; ++nt)
#pragma unroll
      for (int i = 0; i < 4; ++i) s[nt][i] = __expf(s[nt][i] - mrun[i]);

    float rs[4];
#pragma unroll
    for (int i = 0; i < 4; ++i) rs[i] = (s[0][i] + s[1][i]) + (s[2][i] + s[3][i]);
#pragma unroll
    for (int off = 1; off <= 8; off <<= 1)
#pragma unroll
      for (int i = 0; i < 4; ++i) rs[i] += __shfl_xor(rs[i], off);
#pragma unroll
    for (int i = 0; i < 4; ++i) lsum[i] = lsum[i] * alpha[i] + rs[i];

#pragma unroll
    for (int ht = 0; ht < 4; ++ht)
#pragma unroll
      for (int i = 0; i < 4; ++i) o[ht][i] *= alpha[i];

#pragma unroll
    for (int nt = 0; nt < 4; ++nt)
#pragma unroll
      for (int i = 0; i < 4; ++i)
        Ps[sl * 4 + i][nt * 16 + c] = bf16r(s[nt][i]);

    short8 ap0 = *(const short8*)(&Ps[c][sl * 8]);
    short8 ap1 = *(const short8*)(&Ps[c][32 + sl * 8]);

#pragma unroll
    for (int ht = 0; ht < 4; ++ht) {
      o[ht] = MFMA16(ap0, vb[ht][0], o[ht]);
      o[ht] = MFMA16(ap1, vb[ht][1], o[ht]);
    }
  }

  if (direct) {
    float inv[4];
#pragma unroll
    for (int i = 0; i < 4; ++i) inv[i] = 1.0f / lsum[i];
#pragma unroll
    for (int ht = 0; ht < 4; ++ht)
#pragma unroll
      for (int i = 0; i < 4; ++i) {
        const int q = qw + sl * 4 + i;
        out[(size_t)(b * 4096 + q) * 64 + ht * 16 + c] = o[ht][i] * inv[i];
      }
  } else {
    float* sp = part + (size_t)((b * 256 + g) * maxch + ch) * PART_STRIDE;
#pragma unroll
    for (int ht = 0; ht < 4; ++ht)
#pragma unroll
      for (int i = 0; i < 4; ++i)
        sp[(sl * 4 + i) * 64 + ht * 16 + c] = o[ht][i];
    if (c == 0) {
#pragma unroll
      for (int i = 0; i < 4; ++i) {
        sp[1024 + sl * 4 + i] = mrun[i];
        sp[1040 + sl * 4 + i] = lsum[i];
      }
    }
  }
}

// ---------------- Kernel 4: split-KV combine --------------------------------
__global__ __launch_bounds__(256) void combine_kernel(
    const float* __restrict__ part, float* __restrict__ out, int C, int maxch) {
  const int g = blockIdx.x;
  const int b = blockIdx.y;
  const int T = (g >> 2) + 1;
  const int N = (T + C - 1) / C;
  const int r = threadIdx.x >> 4;                 // 0..15
  const int cb = (threadIdx.x & 15) * 4;          // 0..60
  const float* base = part + (size_t)((b * 256 + g) * maxch) * PART_STRIDE;

  float M = -1e30f;
  for (int i = 0; i < N; ++i) M = fmaxf(M, base[i * PART_STRIDE + 1024 + r]);
  float L = 0.f;
  float4v acc = {0.f, 0.f, 0.f, 0.f};
  for (int i = 0; i < N; ++i) {
    const float* s = base + i * PART_STRIDE;
    const float wgt = __expf(s[1024 + r] - M);
    L += wgt * s[1040 + r];
    float4v ov = *(const float4v*)(s + r * 64 + cb);
    acc.x += wgt * ov.x; acc.y += wgt * ov.y;
    acc.z += wgt * ov.z; acc.w += wgt * ov.w;
  }
  const float inv = 1.0f / L;
  float4v res = {acc.x * inv, acc.y * inv, acc.z * inv, acc.w * inv};
  *(float4v*)(out + (size_t)(b * 4096 + g * 16 + r) * 64 + cb) = res;
}

extern "C" void kernel_launch(void* const* d_in, const int* in_sizes, int n_in,
                              void* d_out, int out_size, void* d_ws, size_t ws_size,
                              hipStream_t stream) {
  const float* x  = (const float*)d_in[0];
  const float* Wk = (const float*)d_in[1];
  const float* Wq = (const float*)d_in[2];
  const float* Wv = (const float*)d_in[3];

  char* ws = (char*)d_ws;
  short* WT = (short*)ws;                                  // 393216 B
  short* Kg = (short*)(ws + 393216);                       // 2 MB
  short* Qg = (short*)(ws + 393216 + 2097152);             // 2 MB
  short* Vt = (short*)(ws + 393216 + 2 * 2097152);         // 2 MB
  const size_t part_off = 393216 + 3 * 2097152;            // 6684672
  float* part = (float*)(ws + part_off);

  // choose split-KV chunk size from available workspace (deterministic)
  const size_t slot_bytes = PART_STRIDE * 4;               // 4224
  int C, maxch, direct;
  if (ws_size >= part_off + 8192 * slot_bytes)      { C = 8;  maxch = 8; direct = 0; }
  else if (ws_size >= part_off + 4096 * slot_bytes) { C = 16; maxch = 4; direct = 0; }
  else if (ws_size >= part_off + 2048 * slot_bytes) { C = 32; maxch = 2; direct = 0; }
  else                                              { C = 64; maxch = 1; direct = 1; }

  prep_wt<<<dim3(768), dim3(256), 0, stream>>>(Wk, Wq, Wv, WT);
  proj_kernel<<<dim3(256), dim3(512), 0, stream>>>(x, WT, Kg, Qg, Vt);
  attn_kernel<<<dim3(256, 4, maxch), dim3(64), 0, stream>>>(
      Qg, Kg, Vt, (float*)d_out, part, C, maxch, direct);
  if (!direct)
    combine_kernel<<<dim3(256, 4), dim3(256), 0, stream>>>(
        part, (float*)d_out, C, maxch);
}